// Round 2
// baseline (73.977 us; speedup 1.0000x reference)
//
#include <hip/hip_runtime.h>

#define RHALF 0.70710678118654752440f

struct St { float vr[4]; float vi[4]; int lane; };

// multiply (ar+i*ai) by (c + i*s)
static __device__ __forceinline__ void phase_mul(float& ar, float& ai, float c, float s) {
    float nr = c*ar - s*ai;
    float ni = c*ai + s*ar;
    ar = nr; ai = ni;
}

// new = c*v + (-i*s)*p   (used by RX and IsingXX)
static __device__ __forceinline__ void xxupd(float& ar, float& ai, float pr, float pi, float c, float s) {
    ar = c*ar + s*pi;
    ai = c*ai - s*pr;
}

static __device__ __forceinline__ void rx_pair(float& ar, float& ai, float& br, float& bi, float c, float s) {
    float nar = c*ar + s*bi, nai = c*ai - s*br;
    float nbr = c*br + s*ai, nbi = c*bi - s*ar;
    ar=nar; ai=nai; br=nbr; bi=nbi;
}

static __device__ __forceinline__ void ry_pair(float& ar, float& ai, float& br, float& bi, float c, float s) {
    float nar = c*ar - s*br, nai = c*ai - s*bi;
    float nbr = s*ar + c*br, nbi = s*ai + c*bi;
    ar=nar; ai=nai; br=nbr; bi=nbi;
}

static __device__ __forceinline__ void cswap2(float& ar, float& ai, float& br, float& bi, bool ctl) {
    float n0 = ctl ? br : ar, n1 = ctl ? ar : br;
    float m0 = ctl ? bi : ai, m1 = ctl ? ai : bi;
    ar = n0; br = n1; ai = m0; bi = m1;
}

static __device__ __forceinline__ void swapf(float& a, float& b) { float t=a; a=b; b=t; }

static __device__ __forceinline__ void xx2(float& ar,float& ai,float& br,float& bi,int lm,float c,float s) {
    // partner of (reg a, lane l) is (reg b, lane l^lm) and vice versa
    float pbr = __shfl_xor(ar, lm, 64), pbi = __shfl_xor(ai, lm, 64);
    float par = __shfl_xor(br, lm, 64), pai = __shfl_xor(bi, lm, 64);
    xxupd(ar,ai,par,pai,c,s);
    xxupd(br,bi,pbr,pbi,c,s);
}

// ---- gates; layout: amplitude s = k*64 + lane; qubit q -> bit (7-q) of s
//      qubit0 -> reg bit1, qubit1 -> reg bit0, qubits 2..7 -> lane bits 5..0

static __device__ __forceinline__ void gRZ(St& st, int q, float c, float s) {
    // bit0 amp *= (c - i s); bit1 amp *= (c + i s)
    if (q == 0) {
        phase_mul(st.vr[0],st.vi[0],c,-s); phase_mul(st.vr[1],st.vi[1],c,-s);
        phase_mul(st.vr[2],st.vi[2],c, s); phase_mul(st.vr[3],st.vi[3],c, s);
    } else if (q == 1) {
        phase_mul(st.vr[0],st.vi[0],c,-s); phase_mul(st.vr[2],st.vi[2],c,-s);
        phase_mul(st.vr[1],st.vi[1],c, s); phase_mul(st.vr[3],st.vi[3],c, s);
    } else {
        int ml = 1 << (7-q);
        float sg = (st.lane & ml) ? s : -s;
        phase_mul(st.vr[0],st.vi[0],c,sg);
        phase_mul(st.vr[1],st.vi[1],c,sg);
        phase_mul(st.vr[2],st.vi[2],c,sg);
        phase_mul(st.vr[3],st.vi[3],c,sg);
    }
}

static __device__ __forceinline__ void gRX(St& st, int q, float c, float s) {
    if (q == 0) {
        rx_pair(st.vr[0],st.vi[0],st.vr[2],st.vi[2],c,s);
        rx_pair(st.vr[1],st.vi[1],st.vr[3],st.vi[3],c,s);
    } else if (q == 1) {
        rx_pair(st.vr[0],st.vi[0],st.vr[1],st.vi[1],c,s);
        rx_pair(st.vr[2],st.vi[2],st.vr[3],st.vi[3],c,s);
    } else {
        int ml = 1 << (7-q);
        #pragma unroll
        for (int k=0;k<4;++k) {
            float pr = __shfl_xor(st.vr[k], ml, 64);
            float pi = __shfl_xor(st.vi[k], ml, 64);
            xxupd(st.vr[k], st.vi[k], pr, pi, c, s);
        }
    }
}

static __device__ __forceinline__ void gRY(St& st, int q, float c, float s) {
    if (q == 0) {
        ry_pair(st.vr[0],st.vi[0],st.vr[2],st.vi[2],c,s);
        ry_pair(st.vr[1],st.vi[1],st.vr[3],st.vi[3],c,s);
    } else if (q == 1) {
        ry_pair(st.vr[0],st.vi[0],st.vr[1],st.vi[1],c,s);
        ry_pair(st.vr[2],st.vi[2],st.vr[3],st.vi[3],c,s);
    } else {
        int ml = 1 << (7-q);
        float pc = (st.lane & ml) ? s : -s;   // lo: -s*partner ; hi: +s*partner ; own always c
        #pragma unroll
        for (int k=0;k<4;++k) {
            float pr = __shfl_xor(st.vr[k], ml, 64);
            float pi = __shfl_xor(st.vi[k], ml, 64);
            st.vr[k] = c*st.vr[k] + pc*pr;
            st.vi[k] = c*st.vi[k] + pc*pi;
        }
    }
}

static __device__ __forceinline__ void gCNOT(St& st, int qc, int qt) {
    if (qc <= 1 && qt <= 1) {
        if (qc == 0) { swapf(st.vr[2],st.vr[3]); swapf(st.vi[2],st.vi[3]); }
        else         { swapf(st.vr[1],st.vr[3]); swapf(st.vi[1],st.vi[3]); }
    } else if (qc <= 1) {
        int ml = 1 << (7-qt);
        if (qc == 0) {
            st.vr[2]=__shfl_xor(st.vr[2],ml,64); st.vi[2]=__shfl_xor(st.vi[2],ml,64);
            st.vr[3]=__shfl_xor(st.vr[3],ml,64); st.vi[3]=__shfl_xor(st.vi[3],ml,64);
        } else {
            st.vr[1]=__shfl_xor(st.vr[1],ml,64); st.vi[1]=__shfl_xor(st.vi[1],ml,64);
            st.vr[3]=__shfl_xor(st.vr[3],ml,64); st.vi[3]=__shfl_xor(st.vi[3],ml,64);
        }
    } else if (qt <= 1) {
        int mlc = 1 << (7-qc);
        bool ctl = (st.lane & mlc) != 0;
        if (qt == 0) {
            cswap2(st.vr[0],st.vi[0],st.vr[2],st.vi[2],ctl);
            cswap2(st.vr[1],st.vi[1],st.vr[3],st.vi[3],ctl);
        } else {
            cswap2(st.vr[0],st.vi[0],st.vr[1],st.vi[1],ctl);
            cswap2(st.vr[2],st.vi[2],st.vr[3],st.vi[3],ctl);
        }
    } else {
        int mlt = 1 << (7-qt);
        int mlc = 1 << (7-qc);
        bool ctl = (st.lane & mlc) != 0;
        #pragma unroll
        for (int k=0;k<4;++k) {
            float pr = __shfl_xor(st.vr[k], mlt, 64);
            float pi = __shfl_xor(st.vi[k], mlt, 64);
            st.vr[k] = ctl ? pr : st.vr[k];
            st.vi[k] = ctl ? pi : st.vi[k];
        }
    }
}

static __device__ __forceinline__ void gXX(St& st, int qa, int qb, float c, float s) {
    // partner flips BOTH qubit bits; same coefficient s on every row
    if (qb <= 1) { // only (0,1): partner reg = k^3, same lane
        float p0r=st.vr[3],p0i=st.vi[3],p1r=st.vr[2],p1i=st.vi[2];
        float p2r=st.vr[1],p2i=st.vi[1],p3r=st.vr[0],p3i=st.vi[0];
        xxupd(st.vr[0],st.vi[0],p0r,p0i,c,s);
        xxupd(st.vr[1],st.vi[1],p1r,p1i,c,s);
        xxupd(st.vr[2],st.vi[2],p2r,p2i,c,s);
        xxupd(st.vr[3],st.vi[3],p3r,p3i,c,s);
    } else if (qa <= 1) {
        int lm = 1 << (7-qb);
        if (qa == 0) {
            xx2(st.vr[0],st.vi[0],st.vr[2],st.vi[2],lm,c,s);
            xx2(st.vr[1],st.vi[1],st.vr[3],st.vi[3],lm,c,s);
        } else {
            xx2(st.vr[0],st.vi[0],st.vr[1],st.vi[1],lm,c,s);
            xx2(st.vr[2],st.vi[2],st.vr[3],st.vi[3],lm,c,s);
        }
    } else {
        int lm = (1<<(7-qa)) | (1<<(7-qb));
        #pragma unroll
        for (int k=0;k<4;++k) {
            float pr = __shfl_xor(st.vr[k], lm, 64);
            float pi = __shfl_xor(st.vi[k], lm, 64);
            xxupd(st.vr[k],st.vi[k],pr,pi,c,s);
        }
    }
}

__global__ __launch_bounds__(64) void evolve_kernel(const float* __restrict__ x,
                                                    const float* __restrict__ w,
                                                    const float* __restrict__ cp,
                                                    float2* __restrict__ psi) {
    __shared__ float2 tw[256];   // (cos(w/2), sin(w/2)) per weight
    __shared__ float2 tc[64];    // same for coupling
    int lane = threadIdx.x;

    // batched trig tables (one sincosf per lane-slot instead of per gate)
    #pragma unroll
    for (int k=0;k<4;++k) {
        int idx = k*64 + lane;
        float a = (idx < 210) ? w[idx] : 0.0f;
        float sn, cn; sincosf(0.5f*a, &sn, &cn);
        tw[idx] = make_float2(cn, sn);
    }
    float cv = cp[lane];
    { float sn, cn; sincosf(0.5f*cv, &sn, &cn); tc[lane] = make_float2(cn, sn); }

    // state init: psi = x / ||x||  (pure state; density matrix stays pure since
    // p_flip==0 and adjacency blend picks exactly one unitary branch)
    St st; st.lane = lane;
    float ss = 0.f;
    #pragma unroll
    for (int k=0;k<4;++k) {
        float xv = x[k*64 + lane];
        st.vr[k] = xv; st.vi[k] = 0.f;
        ss += xv*xv;
    }
    #pragma unroll
    for (int m=32;m>0;m>>=1) ss += __shfl_xor(ss, m, 64);
    float inv = 1.0f / sqrtf(ss);
    #pragma unroll
    for (int k=0;k<4;++k) st.vr[k] *= inv;

    // adjacency from coupling (64 entries = 64 lanes)
    float mn = cv, mx = cv;
    #pragma unroll
    for (int m=32;m>0;m>>=1) {
        mn = fminf(mn, __shfl_xor(mn, m, 64));
        mx = fmaxf(mx, __shfl_xor(mx, m, 64));
    }
    unsigned long long adj = __ballot(((cv - mn) / (mx - mn)) > 0.5f);

    __syncthreads();

    // phase 1: rx, ry, rz on every qubit
    #pragma unroll
    for (int q=0;q<8;++q) {
        float2 cs;
        cs = tw[q];      gRX(st, q, cs.x, cs.y);
        cs = tw[q+8];    gRY(st, q, cs.x, cs.y);
        cs = tw[q+16];   gRZ(st, q, cs.x, cs.y);
    }

    // phase 2: IsingXX on every pair (i<j)
    #pragma unroll
    for (int i=0;i<8;++i) {
        #pragma unroll
        for (int j=i+1;j<8;++j) {
            float2 cs = tc[i*8+j];
            gXX(st, i, j, cs.x, cs.y);
        }
    }

    // phase 3: conditional conv+pool blocks
    int count = 0;
    #pragma unroll
    for (int i=0;i<8;++i) {
        #pragma unroll
        for (int j=i+1;j<8;++j) {
            if ((adj >> (i*8 + j)) & 1ull) {
                int pb = 24 + 6*count;
                float2 cs;
                // conv_block(rho, i, j, p[0:3])
                gRZ(st, j, RHALF, -RHALF);           // rz(-pi/2) on j
                gCNOT(st, j, i);
                cs = tw[pb+0]; gRZ(st, i, cs.x, cs.y);
                cs = tw[pb+1]; gRY(st, j, cs.x, cs.y);
                gCNOT(st, i, j);
                cs = tw[pb+2]; gRY(st, j, cs.x, cs.y);
                gCNOT(st, j, i);
                gRZ(st, i, RHALF, RHALF);            // rz(+pi/2) on i
                // pool_block(rho, i, j, p[3:6])
                gRZ(st, j, RHALF, -RHALF);
                gCNOT(st, j, i);
                cs = tw[pb+3]; gRZ(st, i, cs.x, cs.y);
                cs = tw[pb+4]; gRY(st, j, cs.x, cs.y);
                gCNOT(st, i, j);
                cs = tw[pb+5]; gRY(st, j, cs.x, cs.y);
                ++count;
            }
        }
    }

    // write statevector to workspace
    #pragma unroll
    for (int k=0;k<4;++k) psi[k*64+lane] = make_float2(st.vr[k], st.vi[k]);
}

// rho[r,c] = psi[r] * conj(psi[c]); planar layout: out[0:65536]=real, out[65536:]=imag
__global__ __launch_bounds__(256) void outer_planar(const float2* __restrict__ psi,
                                                    float* __restrict__ out) {
    int c = threadIdx.x;
    int r = blockIdx.x;
    float2 pr = psi[r];   // wave-uniform broadcast load
    float2 pc = psi[c];   // coalesced
    int idx = (r<<8) + c;
    out[idx]         = pr.x*pc.x + pr.y*pc.y;
    out[idx + 65536] = pr.y*pc.x - pr.x*pc.y;
}

// real part only (if harness canonicalized complex64 via astype(float32))
__global__ __launch_bounds__(256) void outer_real(const float2* __restrict__ psi,
                                                  float* __restrict__ out) {
    int c = threadIdx.x;
    int r = blockIdx.x;
    float2 pr = psi[r];
    float2 pc = psi[c];
    out[(r<<8) + c] = pr.x*pc.x + pr.y*pc.y;
}

// interleaved fallback (complex64 viewed as float32 pairs)
__global__ __launch_bounds__(256) void outer_interleaved(const float2* __restrict__ psi,
                                                         float2* __restrict__ out) {
    int c = threadIdx.x;
    int r = blockIdx.x;
    float2 pr = psi[r];
    float2 pc = psi[c];
    out[(r<<8) + c] = make_float2(pr.x*pc.x + pr.y*pc.y, pr.y*pc.x - pr.x*pc.y);
}

extern "C" void kernel_launch(void* const* d_in, const int* in_sizes, int n_in,
                              void* d_out, int out_size, void* d_ws, size_t ws_size,
                              hipStream_t stream) {
    (void)in_sizes; (void)n_in; (void)ws_size;
    const float* x  = (const float*)d_in[0];
    const float* w  = (const float*)d_in[1];
    const float* cp = (const float*)d_in[2];
    float2* psi = (float2*)d_ws;   // 256 * 8B = 2KB scratch
    hipLaunchKernelGGL(evolve_kernel, dim3(1), dim3(64), 0, stream, x, w, cp, psi);
    if (out_size == 65536) {
        hipLaunchKernelGGL(outer_real, dim3(256), dim3(256), 0, stream, psi, (float*)d_out);
    } else if (out_size == 131072) {
        hipLaunchKernelGGL(outer_planar, dim3(256), dim3(256), 0, stream, psi, (float*)d_out);
    } else {
        hipLaunchKernelGGL(outer_interleaved, dim3(256), dim3(256), 0, stream, psi, (float2*)d_out);
    }
}

// Round 3
// 68.139 us; speedup vs baseline: 1.0857x; 1.0857x over previous
//
#include <hip/hip_runtime.h>

#define RHALF 0.70710678118654752440f

typedef float2 cpx;

static __device__ __forceinline__ cpx cmul(cpx a, cpx b) {
    return make_float2(a.x*b.x - a.y*b.y, a.x*b.y + a.y*b.x);
}
static __device__ __forceinline__ void cmac(cpx& n, cpx k, cpx a) {
    n.x += k.x*a.x - k.y*a.y;
    n.y += k.x*a.y + k.y*a.x;
}

struct St { float vr[4]; float vi[4]; int lane; };

// new = c*v + (-i*s)*p   (RX / IsingXX row update)
static __device__ __forceinline__ void xxupd(float& ar, float& ai, float pr, float pi, float c, float s) {
    ar = c*ar + s*pi;
    ai = c*ai - s*pr;
}

static __device__ __forceinline__ void xx2(float& ar,float& ai,float& br,float& bi,int lm,float c,float s) {
    float pbr = __shfl_xor(ar, lm, 64), pbi = __shfl_xor(ai, lm, 64);
    float par = __shfl_xor(br, lm, 64), pai = __shfl_xor(bi, lm, 64);
    xxupd(ar,ai,par,pai,c,s);
    xxupd(br,bi,pbr,pbi,c,s);
}

// ---- layout: amplitude s = k*64 + lane; qubit q -> bit (7-q) of s
//      qubit0 -> reg bit1, qubit1 -> reg bit0, qubits 2..7 -> lane bits 5..0

static __device__ __forceinline__ void gXX(St& st, int qa, int qb, float c, float s) {
    if (qb <= 1) { // (0,1): partner reg = k^3, same lane
        float p0r=st.vr[3],p0i=st.vi[3],p1r=st.vr[2],p1i=st.vi[2];
        float p2r=st.vr[1],p2i=st.vi[1],p3r=st.vr[0],p3i=st.vi[0];
        xxupd(st.vr[0],st.vi[0],p0r,p0i,c,s);
        xxupd(st.vr[1],st.vi[1],p1r,p1i,c,s);
        xxupd(st.vr[2],st.vi[2],p2r,p2i,c,s);
        xxupd(st.vr[3],st.vi[3],p3r,p3i,c,s);
    } else if (qa <= 1) {
        int lm = 1 << (7-qb);
        if (qa == 0) {
            xx2(st.vr[0],st.vi[0],st.vr[2],st.vi[2],lm,c,s);
            xx2(st.vr[1],st.vi[1],st.vr[3],st.vi[3],lm,c,s);
        } else {
            xx2(st.vr[0],st.vi[0],st.vr[1],st.vi[1],lm,c,s);
            xx2(st.vr[2],st.vi[2],st.vr[3],st.vi[3],lm,c,s);
        }
    } else {
        int lm = (1<<(7-qa)) | (1<<(7-qb));
        #pragma unroll
        for (int k=0;k<4;++k) {
            float pr = __shfl_xor(st.vr[k], lm, 64);
            float pi = __shfl_xor(st.vi[k], lm, 64);
            xxupd(st.vr[k],st.vi[k],pr,pi,c,s);
        }
    }
}

// ---- composite two-qubit gate application, basis v = 2*b_i + b_j ----

// both qubits in lane bits (i,j >= 2)
static __device__ __forceinline__ void applyBlockLL(St& st, const cpx* bm, int p, int i, int j) {
    int mi = 1 << (7-i), mj = 1 << (7-j);
    int r = ((st.lane & mi) ? 2 : 0) | ((st.lane & mj) ? 1 : 0);
    const cpx* row = bm + p*16 + r*4;
    cpx K0 = row[r], K1 = row[r^1], K2 = row[r^2], K3 = row[r^3];
    #pragma unroll
    for (int k=0;k<4;++k) {
        float p1r = __shfl_xor(st.vr[k], mj, 64),    p1i = __shfl_xor(st.vi[k], mj, 64);
        float p2r = __shfl_xor(st.vr[k], mi, 64),    p2i = __shfl_xor(st.vi[k], mi, 64);
        float p3r = __shfl_xor(st.vr[k], mi|mj, 64), p3i = __shfl_xor(st.vi[k], mi|mj, 64);
        cpx n = make_float2(0.f,0.f);
        cmac(n, K0, make_float2(st.vr[k], st.vi[k]));
        cmac(n, K1, make_float2(p1r,p1i));
        cmac(n, K2, make_float2(p2r,p2i));
        cmac(n, K3, make_float2(p3r,p3i));
        st.vr[k] = n.x; st.vi[k] = n.y;
    }
}

// i in {0,1} (register bit), j >= 2 (lane bit)
static __device__ __forceinline__ void applyBlockMixed(St& st, const cpx* bm, int p, int i, int j) {
    int mj = 1 << (7-j);
    int bj = (st.lane & mj) ? 1 : 0;
    const cpx* base = bm + p*16;
    cpx lo0 = base[bj*4+0], lo1 = base[bj*4+1], lo2 = base[bj*4+2], lo3 = base[bj*4+3];
    cpx hi0 = base[(2+bj)*4+0], hi1 = base[(2+bj)*4+1], hi2 = base[(2+bj)*4+2], hi3 = base[(2+bj)*4+3];
    // columns: own-lane (b_j'=bj) vs shuffled (b_j'=1-bj), for b_i'=0/1
    cpx lo_o0 = bj ? lo1 : lo0;  cpx lo_s0 = bj ? lo0 : lo1;
    cpx lo_o1 = bj ? lo3 : lo2;  cpx lo_s1 = bj ? lo2 : lo3;
    cpx hi_o0 = bj ? hi1 : hi0;  cpx hi_s0 = bj ? hi0 : hi1;
    cpx hi_o1 = bj ? hi3 : hi2;  cpx hi_s1 = bj ? hi2 : hi3;
    float sr[4], si[4];
    #pragma unroll
    for (int k=0;k<4;++k) { sr[k] = __shfl_xor(st.vr[k], mj, 64); si[k] = __shfl_xor(st.vi[k], mj, 64); }
    int ri = (i==0) ? 2 : 1;
    #pragma unroll
    for (int t=0; t<2; ++t) {
        int k0 = (i==0) ? t : (t*2);
        int k1 = k0 | ri;
        cpx a0 = make_float2(st.vr[k0], st.vi[k0]);
        cpx a1 = make_float2(st.vr[k1], st.vi[k1]);
        cpx s0 = make_float2(sr[k0], si[k0]);
        cpx s1 = make_float2(sr[k1], si[k1]);
        cpx n0 = make_float2(0.f,0.f), n1 = make_float2(0.f,0.f);
        cmac(n0, lo_o0, a0); cmac(n0, lo_s0, s0); cmac(n0, lo_o1, a1); cmac(n0, lo_s1, s1);
        cmac(n1, hi_o0, a0); cmac(n1, hi_s0, s0); cmac(n1, hi_o1, a1); cmac(n1, hi_s1, s1);
        st.vr[k0]=n0.x; st.vi[k0]=n0.y; st.vr[k1]=n1.x; st.vi[k1]=n1.y;
    }
}

// pair (0,1): both in register bits, v = k
static __device__ __forceinline__ void applyBlock01(St& st, const cpx* bm, int p) {
    const cpx* base = bm + p*16;
    cpx a[4];
    #pragma unroll
    for (int k=0;k<4;++k) a[k] = make_float2(st.vr[k], st.vi[k]);
    #pragma unroll
    for (int r=0;r<4;++r) {
        cpx n = make_float2(0.f,0.f);
        #pragma unroll
        for (int c=0;c<4;++c) cmac(n, base[r*4+c], a[c]);
        st.vr[r]=n.x; st.vi[r]=n.y;
    }
}

__global__ __launch_bounds__(64) void evolve_kernel(const float* __restrict__ x,
                                                    const float* __restrict__ w,
                                                    const float* __restrict__ cp,
                                                    float2* __restrict__ psi) {
    __shared__ cpx tc[64];        // (cos,sin) of coupling/2
    __shared__ cpx u1[32];        // fused single-qubit 2x2 per qubit
    __shared__ cpx bmat[28*16];   // composite conv+pool 4x4 per pair
    int lane = threadIdx.x;

    // ---- state init: psi = x/||x|| ----
    St st; st.lane = lane;
    float ss = 0.f;
    #pragma unroll
    for (int k=0;k<4;++k) {
        float xv = x[k*64 + lane];
        st.vr[k] = xv; st.vi[k] = 0.f;
        ss += xv*xv;
    }
    #pragma unroll
    for (int m=32;m>0;m>>=1) ss += __shfl_xor(ss, m, 64);
    float inv = 1.0f / sqrtf(ss);
    #pragma unroll
    for (int k=0;k<4;++k) st.vr[k] *= inv;

    // ---- coupling trig + adjacency ----
    float cv = cp[lane];
    { float sn, cn; sincosf(0.5f*cv, &sn, &cn); tc[lane] = make_float2(cn, sn); }
    float mn = cv, mx = cv;
    #pragma unroll
    for (int m=32;m>0;m>>=1) {
        mn = fminf(mn, __shfl_xor(mn, m, 64));
        mx = fmaxf(mx, __shfl_xor(mx, m, 64));
    }
    unsigned long long adj64 = __ballot(((cv - mn) / (mx - mn)) > 0.5f);

    // pair-order mask + per-pair parameter prefix (lane p <-> pair p)
    int ii = 0, jj = 0;
    if (lane < 28) {
        int rem = lane;
        while (rem >= 7-ii) { rem -= 7-ii; ++ii; }
        jj = ii + 1 + rem;
    }
    unsigned int f = (lane < 28) ? (unsigned int)((adj64 >> (ii*8 + jj)) & 1ull) : 0u;
    unsigned long long pmw = __ballot(f != 0u);
    unsigned int pm = (unsigned int)(pmw & 0xFFFFFFFull);
    int prefix = __popcll(pmw & ((1ull << lane) - 1ull));

    // ---- fused single-qubit U = Rz*Ry*Rx, built by lanes 0..7 ----
    {
        int q = lane & 7;
        float sn0,cn0,sn1,cn1,sn2,cn2;
        sincosf(0.5f*w[q],    &sn0, &cn0);
        sincosf(0.5f*w[q+8],  &sn1, &cn1);
        sincosf(0.5f*w[q+16], &sn2, &cn2);
        cpx A00 = make_float2( cn1*cn0,  sn1*sn0);
        cpx A01 = make_float2(-sn1*cn0, -cn1*sn0);
        cpx A10 = make_float2( sn1*cn0, -cn1*sn0);
        cpx A11 = make_float2( cn1*cn0, -sn1*sn0);
        cpx e0 = make_float2(cn2,-sn2), e1 = make_float2(cn2, sn2);
        if (lane < 8) {
            u1[q*4+0] = cmul(e0,A00); u1[q*4+1] = cmul(e0,A01);
            u1[q*4+2] = cmul(e1,A10); u1[q*4+3] = cmul(e1,A11);
        }
    }

    // ---- composite conv+pool 4x4, one lane per pair (basis-local: no (i,j) dep) ----
    if (lane < 28) {
        int idx = 24 + 6*prefix;
        float s0,c0,s1,c1,s2,c2,s3,c3,s4,c4,s5,c5;
        sincosf(0.5f*w[idx+0], &s0, &c0);
        sincosf(0.5f*w[idx+1], &s1, &c1);
        sincosf(0.5f*w[idx+2], &s2, &c2);
        sincosf(0.5f*w[idx+3], &s3, &c3);
        sincosf(0.5f*w[idx+4], &s4, &c4);
        sincosf(0.5f*w[idx+5], &s5, &c5);
        cpx m[16];
        #pragma unroll
        for (int e=0;e<16;++e) m[e] = make_float2(0.f,0.f);
        // G1: rz_j(-pi/2): diag phases e^{+i pi/4} (b_j=0) / e^{-i pi/4} (b_j=1)
        m[0]  = make_float2(RHALF,  RHALF);
        m[5]  = make_float2(RHALF, -RHALF);
        m[10] = make_float2(RHALF,  RHALF);
        m[15] = make_float2(RHALF, -RHALF);
        #define RSWAP(a,b) { _Pragma("unroll") for (int c_=0;c_<4;++c_){ cpx t_=m[(a)*4+c_]; m[(a)*4+c_]=m[(b)*4+c_]; m[(b)*4+c_]=t_; } }
        #define DIAG_I(e0x,e0y,e1x,e1y) { cpx ea_=make_float2(e0x,e0y), eb_=make_float2(e1x,e1y); \
            _Pragma("unroll") for (int e_=0;e_<8;++e_)  m[e_]   = cmul(ea_, m[e_]); \
            _Pragma("unroll") for (int e_=8;e_<16;++e_) m[e_]   = cmul(eb_, m[e_]); }
        #define DIAG_J(e0x,e0y,e1x,e1y) { cpx ea_=make_float2(e0x,e0y), eb_=make_float2(e1x,e1y); \
            _Pragma("unroll") for (int c_=0;c_<4;++c_){ m[c_]=cmul(ea_,m[c_]); m[8+c_]=cmul(ea_,m[8+c_]); \
                                                        m[4+c_]=cmul(eb_,m[4+c_]); m[12+c_]=cmul(eb_,m[12+c_]); } }
        #define RY_J(cc,sc) { _Pragma("unroll") for (int c_=0;c_<4;++c_){ \
            cpx a_=m[c_],   b_=m[4+c_];  m[c_]  =make_float2((cc)*a_.x-(sc)*b_.x,(cc)*a_.y-(sc)*b_.y); \
                                         m[4+c_]=make_float2((sc)*a_.x+(cc)*b_.x,(sc)*a_.y+(cc)*b_.y); \
            cpx d_=m[8+c_], e_=m[12+c_]; m[8+c_] =make_float2((cc)*d_.x-(sc)*e_.x,(cc)*d_.y-(sc)*e_.y); \
                                         m[12+c_]=make_float2((sc)*d_.x+(cc)*e_.x,(sc)*d_.y+(cc)*e_.y); } }
        RSWAP(1,3)                      // CNOT j->i
        DIAG_I(c0,-s0, c0, s0)          // rz(p0) on i
        RY_J(c1,s1)                     // ry(p1) on j
        RSWAP(2,3)                      // CNOT i->j
        RY_J(c2,s2)                     // ry(p2) on j
        RSWAP(1,3)                      // CNOT j->i
        DIAG_I(RHALF,-RHALF, RHALF,RHALF)   // rz(+pi/2) on i
        DIAG_J(RHALF,RHALF, RHALF,-RHALF)   // rz(-pi/2) on j (pool)
        RSWAP(1,3)                      // CNOT j->i
        DIAG_I(c3,-s3, c3, s3)          // rz(p3) on i
        RY_J(c4,s4)                     // ry(p4) on j
        RSWAP(2,3)                      // CNOT i->j
        RY_J(c5,s5)                     // ry(p5) on j
        #pragma unroll
        for (int e=0;e<16;++e) bmat[lane*16+e] = m[e];
        #undef RSWAP
        #undef DIAG_I
        #undef DIAG_J
        #undef RY_J
    }

    __syncthreads();

    // ---- phase 1: fused rx*ry*rz per qubit ----
    #pragma unroll
    for (int q=0;q<8;++q) {
        cpx U00=u1[q*4+0], U01=u1[q*4+1], U10=u1[q*4+2], U11=u1[q*4+3];
        if (q >= 2) {
            int ml = 1 << (7-q);
            bool hi = (lane & ml) != 0;
            cpx A = hi ? U11 : U00;
            cpx B = hi ? U10 : U01;
            #pragma unroll
            for (int k=0;k<4;++k) {
                float pr = __shfl_xor(st.vr[k], ml, 64);
                float pi = __shfl_xor(st.vi[k], ml, 64);
                cpx n = make_float2(0.f,0.f);
                cmac(n, A, make_float2(st.vr[k], st.vi[k]));
                cmac(n, B, make_float2(pr, pi));
                st.vr[k]=n.x; st.vi[k]=n.y;
            }
        } else {
            int ri = (q==0) ? 2 : 1;
            #pragma unroll
            for (int t=0;t<2;++t) {
                int k0 = (q==0) ? t : (t*2);
                int k1 = k0 | ri;
                cpx a = make_float2(st.vr[k0], st.vi[k0]);
                cpx b = make_float2(st.vr[k1], st.vi[k1]);
                cpx n0 = make_float2(0.f,0.f), n1 = make_float2(0.f,0.f);
                cmac(n0, U00, a); cmac(n0, U01, b);
                cmac(n1, U10, a); cmac(n1, U11, b);
                st.vr[k0]=n0.x; st.vi[k0]=n0.y; st.vr[k1]=n1.x; st.vi[k1]=n1.y;
            }
        }
    }

    // ---- phase 2: IsingXX, tournament order (all XX commute; rounds of 4 disjoint pairs -> ILP) ----
    {
        constexpr int XI[28] = {0,1,2,3, 1,0,3,4, 2,1,0,5, 3,2,1,0, 4,3,2,0, 5,4,0,1, 6,0,1,2};
        constexpr int XJ[28] = {7,6,5,4, 7,2,6,5, 7,3,4,6, 7,4,5,6, 7,5,6,1, 7,6,3,2, 7,5,4,3};
        #pragma unroll
        for (int g=0; g<28; ++g) {
            cpx cs = tc[XI[g]*8 + XJ[g]];
            gXX(st, XI[g], XJ[g], cs.x, cs.y);
        }
    }

    // ---- phase 3: composite conv+pool per active pair, reference order ----
    {
        constexpr int PI3[28] = {0,0,0,0,0,0,0, 1,1,1,1,1,1, 2,2,2,2,2, 3,3,3,3, 4,4,4, 5,5, 6};
        constexpr int PJ3[28] = {1,2,3,4,5,6,7, 2,3,4,5,6,7, 3,4,5,6,7, 4,5,6,7, 5,6,7, 6,7, 7};
        #pragma unroll
        for (int p=0;p<28;++p) {
            if ((pm >> p) & 1u) {
                const int i = PI3[p], j = PJ3[p];
                if (i >= 2)      applyBlockLL(st, bmat, p, i, j);
                else if (j >= 2) applyBlockMixed(st, bmat, p, i, j);
                else             applyBlock01(st, bmat, p);
            }
        }
    }

    // ---- write statevector ----
    #pragma unroll
    for (int k=0;k<4;++k) psi[k*64+lane] = make_float2(st.vr[k], st.vi[k]);
}

// rho[r,c] = psi[r] * conj(psi[c]); planar: out[0:65536]=real, out[65536:]=imag
__global__ __launch_bounds__(256) void outer_planar(const float2* __restrict__ psi,
                                                    float* __restrict__ out) {
    int c = threadIdx.x;
    int r = blockIdx.x;
    float2 pr = psi[r];
    float2 pc = psi[c];
    int idx = (r<<8) + c;
    out[idx]         = pr.x*pc.x + pr.y*pc.y;
    out[idx + 65536] = pr.y*pc.x - pr.x*pc.y;
}

__global__ __launch_bounds__(256) void outer_real(const float2* __restrict__ psi,
                                                  float* __restrict__ out) {
    int c = threadIdx.x;
    int r = blockIdx.x;
    float2 pr = psi[r];
    float2 pc = psi[c];
    out[(r<<8) + c] = pr.x*pc.x + pr.y*pc.y;
}

__global__ __launch_bounds__(256) void outer_interleaved(const float2* __restrict__ psi,
                                                         float2* __restrict__ out) {
    int c = threadIdx.x;
    int r = blockIdx.x;
    float2 pr = psi[r];
    float2 pc = psi[c];
    out[(r<<8) + c] = make_float2(pr.x*pc.x + pr.y*pc.y, pr.y*pc.x - pr.x*pc.y);
}

extern "C" void kernel_launch(void* const* d_in, const int* in_sizes, int n_in,
                              void* d_out, int out_size, void* d_ws, size_t ws_size,
                              hipStream_t stream) {
    (void)in_sizes; (void)n_in; (void)ws_size;
    const float* x  = (const float*)d_in[0];
    const float* w  = (const float*)d_in[1];
    const float* cp = (const float*)d_in[2];
    float2* psi = (float2*)d_ws;   // 2 KB scratch
    hipLaunchKernelGGL(evolve_kernel, dim3(1), dim3(64), 0, stream, x, w, cp, psi);
    if (out_size == 65536) {
        hipLaunchKernelGGL(outer_real, dim3(256), dim3(256), 0, stream, psi, (float*)d_out);
    } else if (out_size == 131072) {
        hipLaunchKernelGGL(outer_planar, dim3(256), dim3(256), 0, stream, psi, (float*)d_out);
    } else {
        hipLaunchKernelGGL(outer_interleaved, dim3(256), dim3(256), 0, stream, psi, (float2*)d_out);
    }
}

// Round 4
// 67.745 us; speedup vs baseline: 1.0920x; 1.0058x over previous
//
#include <hip/hip_runtime.h>

#define RHALF 0.70710678118654752440f
#define INV2PI 0.15915494309189535f

typedef float2 cpx;

static __device__ __forceinline__ cpx cmul(cpx a, cpx b) {
    return make_float2(a.x*b.x - a.y*b.y, a.x*b.y + a.y*b.x);
}
static __device__ __forceinline__ void cmac(cpx& n, cpx k, cpx a) {
    n.x += k.x*a.x - k.y*a.y;
    n.y += k.x*a.y + k.y*a.x;
}

// fast sincos: args are in [0, 0.5] rad (half of uniform[0,1) angles) -> no range
// reduction needed; v_sin_f32/v_cos_f32 take revolutions. ~1e-6 abs error.
static __device__ __forceinline__ void fsc(float a, float& s, float& c) {
    float r = a * INV2PI;
    s = __builtin_amdgcn_sinf(r);
    c = __builtin_amdgcn_cosf(r);
}

struct St { float vr[4]; float vi[4]; int lane; };

// new = c*v + (-i*s)*p   (RX / IsingXX row update)
static __device__ __forceinline__ void xxupd(float& ar, float& ai, float pr, float pi, float c, float s) {
    ar = c*ar + s*pi;
    ai = c*ai - s*pr;
}

static __device__ __forceinline__ void xx2(float& ar,float& ai,float& br,float& bi,int lm,float c,float s) {
    float pbr = __shfl_xor(ar, lm, 64), pbi = __shfl_xor(ai, lm, 64);
    float par = __shfl_xor(br, lm, 64), pai = __shfl_xor(bi, lm, 64);
    xxupd(ar,ai,par,pai,c,s);
    xxupd(br,bi,pbr,pbi,c,s);
}

// ---- layout: amplitude s = k*64 + lane; qubit q -> bit (7-q) of s
//      qubit0 -> reg bit1, qubit1 -> reg bit0, qubits 2..7 -> lane bits 5..0

static __device__ __forceinline__ void gXX(St& st, int qa, int qb, float c, float s) {
    if (qb <= 1) { // (0,1): partner reg = k^3, same lane
        float p0r=st.vr[3],p0i=st.vi[3],p1r=st.vr[2],p1i=st.vi[2];
        float p2r=st.vr[1],p2i=st.vi[1],p3r=st.vr[0],p3i=st.vi[0];
        xxupd(st.vr[0],st.vi[0],p0r,p0i,c,s);
        xxupd(st.vr[1],st.vi[1],p1r,p1i,c,s);
        xxupd(st.vr[2],st.vi[2],p2r,p2i,c,s);
        xxupd(st.vr[3],st.vi[3],p3r,p3i,c,s);
    } else if (qa <= 1) {
        int lm = 1 << (7-qb);
        if (qa == 0) {
            xx2(st.vr[0],st.vi[0],st.vr[2],st.vi[2],lm,c,s);
            xx2(st.vr[1],st.vi[1],st.vr[3],st.vi[3],lm,c,s);
        } else {
            xx2(st.vr[0],st.vi[0],st.vr[1],st.vi[1],lm,c,s);
            xx2(st.vr[2],st.vi[2],st.vr[3],st.vi[3],lm,c,s);
        }
    } else {
        int lm = (1<<(7-qa)) | (1<<(7-qb));
        #pragma unroll
        for (int k=0;k<4;++k) {
            float pr = __shfl_xor(st.vr[k], lm, 64);
            float pi = __shfl_xor(st.vi[k], lm, 64);
            xxupd(st.vr[k],st.vi[k],pr,pi,c,s);
        }
    }
}

// ---- composite two-qubit gate application, basis v = 2*b_i + b_j ----

static __device__ __forceinline__ void applyBlockLL(St& st, const cpx* bm, int p, int i, int j) {
    int mi = 1 << (7-i), mj = 1 << (7-j);
    int r = ((st.lane & mi) ? 2 : 0) | ((st.lane & mj) ? 1 : 0);
    const cpx* row = bm + p*16 + r*4;
    cpx K0 = row[r], K1 = row[r^1], K2 = row[r^2], K3 = row[r^3];
    #pragma unroll
    for (int k=0;k<4;++k) {
        float p1r = __shfl_xor(st.vr[k], mj, 64),    p1i = __shfl_xor(st.vi[k], mj, 64);
        float p2r = __shfl_xor(st.vr[k], mi, 64),    p2i = __shfl_xor(st.vi[k], mi, 64);
        float p3r = __shfl_xor(st.vr[k], mi|mj, 64), p3i = __shfl_xor(st.vi[k], mi|mj, 64);
        cpx n = make_float2(0.f,0.f);
        cmac(n, K0, make_float2(st.vr[k], st.vi[k]));
        cmac(n, K1, make_float2(p1r,p1i));
        cmac(n, K2, make_float2(p2r,p2i));
        cmac(n, K3, make_float2(p3r,p3i));
        st.vr[k] = n.x; st.vi[k] = n.y;
    }
}

static __device__ __forceinline__ void applyBlockMixed(St& st, const cpx* bm, int p, int i, int j) {
    int mj = 1 << (7-j);
    int bj = (st.lane & mj) ? 1 : 0;
    const cpx* base = bm + p*16;
    cpx lo0 = base[bj*4+0], lo1 = base[bj*4+1], lo2 = base[bj*4+2], lo3 = base[bj*4+3];
    cpx hi0 = base[(2+bj)*4+0], hi1 = base[(2+bj)*4+1], hi2 = base[(2+bj)*4+2], hi3 = base[(2+bj)*4+3];
    cpx lo_o0 = bj ? lo1 : lo0;  cpx lo_s0 = bj ? lo0 : lo1;
    cpx lo_o1 = bj ? lo3 : lo2;  cpx lo_s1 = bj ? lo2 : lo3;
    cpx hi_o0 = bj ? hi1 : hi0;  cpx hi_s0 = bj ? hi0 : hi1;
    cpx hi_o1 = bj ? hi3 : hi2;  cpx hi_s1 = bj ? hi2 : hi3;
    float sr[4], si[4];
    #pragma unroll
    for (int k=0;k<4;++k) { sr[k] = __shfl_xor(st.vr[k], mj, 64); si[k] = __shfl_xor(st.vi[k], mj, 64); }
    int ri = (i==0) ? 2 : 1;
    #pragma unroll
    for (int t=0; t<2; ++t) {
        int k0 = (i==0) ? t : (t*2);
        int k1 = k0 | ri;
        cpx a0 = make_float2(st.vr[k0], st.vi[k0]);
        cpx a1 = make_float2(st.vr[k1], st.vi[k1]);
        cpx s0 = make_float2(sr[k0], si[k0]);
        cpx s1 = make_float2(sr[k1], si[k1]);
        cpx n0 = make_float2(0.f,0.f), n1 = make_float2(0.f,0.f);
        cmac(n0, lo_o0, a0); cmac(n0, lo_s0, s0); cmac(n0, lo_o1, a1); cmac(n0, lo_s1, s1);
        cmac(n1, hi_o0, a0); cmac(n1, hi_s0, s0); cmac(n1, hi_o1, a1); cmac(n1, hi_s1, s1);
        st.vr[k0]=n0.x; st.vi[k0]=n0.y; st.vr[k1]=n1.x; st.vi[k1]=n1.y;
    }
}

static __device__ __forceinline__ void applyBlock01(St& st, const cpx* bm, int p) {
    const cpx* base = bm + p*16;
    cpx a[4];
    #pragma unroll
    for (int k=0;k<4;++k) a[k] = make_float2(st.vr[k], st.vi[k]);
    #pragma unroll
    for (int r=0;r<4;++r) {
        cpx n = make_float2(0.f,0.f);
        #pragma unroll
        for (int c=0;c<4;++c) cmac(n, base[r*4+c], a[c]);
        st.vr[r]=n.x; st.vi[r]=n.y;
    }
}

__global__ __launch_bounds__(64) void evolve_kernel(const float* __restrict__ x,
                                                    const float* __restrict__ w,
                                                    const float* __restrict__ cp,
                                                    float2* __restrict__ psi) {
    __shared__ float wsh[256];    // staged weights (global loads issued at t=0)
    __shared__ cpx tc[64];        // (cos,sin) of coupling/2
    __shared__ cpx u1[32];        // fused single-qubit 2x2 per qubit
    __shared__ cpx bmat[28*16];   // composite conv+pool 4x4 per pair
    int lane = threadIdx.x;

    // ---- issue ALL independent global loads immediately (one HBM round trip) ----
    float xv[4], wv[4];
    #pragma unroll
    for (int k=0;k<4;++k) {
        int idx = k*64 + lane;
        xv[k] = x[idx];
        wv[k] = (idx < 210) ? w[idx] : 0.0f;
    }
    float cv = cp[lane];
    #pragma unroll
    for (int k=0;k<4;++k) wsh[k*64+lane] = wv[k];

    // ---- state init: psi = x/||x|| (pure state; stays pure: p_flip==0 and the
    //      adjacency blend picks exactly one unitary branch) ----
    St st; st.lane = lane;
    float ss = 0.f;
    #pragma unroll
    for (int k=0;k<4;++k) { st.vr[k] = xv[k]; st.vi[k] = 0.f; ss += xv[k]*xv[k]; }
    #pragma unroll
    for (int m=32;m>0;m>>=1) ss += __shfl_xor(ss, m, 64);
    float inv = 1.0f / sqrtf(ss);
    #pragma unroll
    for (int k=0;k<4;++k) st.vr[k] *= inv;

    // ---- coupling trig + adjacency ----
    { float sn, cn; fsc(0.5f*cv, sn, cn); tc[lane] = make_float2(cn, sn); }
    float mn = cv, mx = cv;
    #pragma unroll
    for (int m=32;m>0;m>>=1) {
        mn = fminf(mn, __shfl_xor(mn, m, 64));
        mx = fmaxf(mx, __shfl_xor(mx, m, 64));
    }
    unsigned long long adj64 = __ballot(((cv - mn) / (mx - mn)) > 0.5f);

    // pair-order mask + per-pair parameter prefix (lane p <-> pair p)
    int ii = 0, jj = 0;
    if (lane < 28) {
        int rem = lane;
        while (rem >= 7-ii) { rem -= 7-ii; ++ii; }
        jj = ii + 1 + rem;
    }
    unsigned int f = (lane < 28) ? (unsigned int)((adj64 >> (ii*8 + jj)) & 1ull) : 0u;
    unsigned long long pmw = __ballot(f != 0u);
    unsigned int pm = (unsigned int)(pmw & 0xFFFFFFFull);
    int prefix = __popcll(pmw & ((1ull << lane) - 1ull));

    __syncthreads();   // wsh staged

    // ---- fused single-qubit U = Rz*Ry*Rx, built by lanes 0..7 (LDS reads) ----
    if (lane < 8) {
        int q = lane;
        float sn0,cn0,sn1,cn1,sn2,cn2;
        fsc(0.5f*wsh[q],    sn0, cn0);
        fsc(0.5f*wsh[q+8],  sn1, cn1);
        fsc(0.5f*wsh[q+16], sn2, cn2);
        cpx A00 = make_float2( cn1*cn0,  sn1*sn0);
        cpx A01 = make_float2(-sn1*cn0, -cn1*sn0);
        cpx A10 = make_float2( sn1*cn0, -cn1*sn0);
        cpx A11 = make_float2( cn1*cn0, -sn1*sn0);
        cpx e0 = make_float2(cn2,-sn2), e1 = make_float2(cn2, sn2);
        u1[q*4+0] = cmul(e0,A00); u1[q*4+1] = cmul(e0,A01);
        u1[q*4+2] = cmul(e1,A10); u1[q*4+3] = cmul(e1,A11);
    }

    // ---- composite conv+pool 4x4, one lane per pair (basis-local) ----
    if (lane < 28) {
        int idx = 24 + 6*prefix;
        float s0,c0,s1,c1,s2,c2,s3,c3,s4,c4,s5,c5;
        fsc(0.5f*wsh[idx+0], s0, c0);
        fsc(0.5f*wsh[idx+1], s1, c1);
        fsc(0.5f*wsh[idx+2], s2, c2);
        fsc(0.5f*wsh[idx+3], s3, c3);
        fsc(0.5f*wsh[idx+4], s4, c4);
        fsc(0.5f*wsh[idx+5], s5, c5);
        cpx m[16];
        #pragma unroll
        for (int e=0;e<16;++e) m[e] = make_float2(0.f,0.f);
        // G1: rz_j(-pi/2): diag e^{+i pi/4} (b_j=0) / e^{-i pi/4} (b_j=1)
        m[0]  = make_float2(RHALF,  RHALF);
        m[5]  = make_float2(RHALF, -RHALF);
        m[10] = make_float2(RHALF,  RHALF);
        m[15] = make_float2(RHALF, -RHALF);
        #define RSWAP(a,b) { _Pragma("unroll") for (int c_=0;c_<4;++c_){ cpx t_=m[(a)*4+c_]; m[(a)*4+c_]=m[(b)*4+c_]; m[(b)*4+c_]=t_; } }
        #define DIAG_I(e0x,e0y,e1x,e1y) { cpx ea_=make_float2(e0x,e0y), eb_=make_float2(e1x,e1y); \
            _Pragma("unroll") for (int e_=0;e_<8;++e_)  m[e_]   = cmul(ea_, m[e_]); \
            _Pragma("unroll") for (int e_=8;e_<16;++e_) m[e_]   = cmul(eb_, m[e_]); }
        #define DIAG_J(e0x,e0y,e1x,e1y) { cpx ea_=make_float2(e0x,e0y), eb_=make_float2(e1x,e1y); \
            _Pragma("unroll") for (int c_=0;c_<4;++c_){ m[c_]=cmul(ea_,m[c_]); m[8+c_]=cmul(ea_,m[8+c_]); \
                                                        m[4+c_]=cmul(eb_,m[4+c_]); m[12+c_]=cmul(eb_,m[12+c_]); } }
        #define RY_J(cc,sc) { _Pragma("unroll") for (int c_=0;c_<4;++c_){ \
            cpx a_=m[c_],   b_=m[4+c_];  m[c_]  =make_float2((cc)*a_.x-(sc)*b_.x,(cc)*a_.y-(sc)*b_.y); \
                                         m[4+c_]=make_float2((sc)*a_.x+(cc)*b_.x,(sc)*a_.y+(cc)*b_.y); \
            cpx d_=m[8+c_], e_=m[12+c_]; m[8+c_] =make_float2((cc)*d_.x-(sc)*e_.x,(cc)*d_.y-(sc)*e_.y); \
                                         m[12+c_]=make_float2((sc)*d_.x+(cc)*e_.x,(sc)*d_.y+(cc)*e_.y); } }
        RSWAP(1,3)                          // CNOT j->i
        DIAG_I(c0,-s0, c0, s0)              // rz(p0) on i
        RY_J(c1,s1)                         // ry(p1) on j
        RSWAP(2,3)                          // CNOT i->j
        RY_J(c2,s2)                         // ry(p2) on j
        RSWAP(1,3)                          // CNOT j->i
        DIAG_I(RHALF,-RHALF, RHALF,RHALF)   // rz(+pi/2) on i
        DIAG_J(RHALF,RHALF, RHALF,-RHALF)   // rz(-pi/2) on j (pool)
        RSWAP(1,3)                          // CNOT j->i
        DIAG_I(c3,-s3, c3, s3)              // rz(p3) on i
        RY_J(c4,s4)                         // ry(p4) on j
        RSWAP(2,3)                          // CNOT i->j
        RY_J(c5,s5)                         // ry(p5) on j
        #pragma unroll
        for (int e=0;e<16;++e) bmat[lane*16+e] = m[e];
        #undef RSWAP
        #undef DIAG_I
        #undef DIAG_J
        #undef RY_J
    }

    __syncthreads();

    // ---- phase 1: fused rx*ry*rz per qubit ----
    #pragma unroll
    for (int q=0;q<8;++q) {
        cpx U00=u1[q*4+0], U01=u1[q*4+1], U10=u1[q*4+2], U11=u1[q*4+3];
        if (q >= 2) {
            int ml = 1 << (7-q);
            bool hi = (lane & ml) != 0;
            cpx A = hi ? U11 : U00;
            cpx B = hi ? U10 : U01;
            #pragma unroll
            for (int k=0;k<4;++k) {
                float pr = __shfl_xor(st.vr[k], ml, 64);
                float pi = __shfl_xor(st.vi[k], ml, 64);
                cpx n = make_float2(0.f,0.f);
                cmac(n, A, make_float2(st.vr[k], st.vi[k]));
                cmac(n, B, make_float2(pr, pi));
                st.vr[k]=n.x; st.vi[k]=n.y;
            }
        } else {
            int ri = (q==0) ? 2 : 1;
            #pragma unroll
            for (int t=0;t<2;++t) {
                int k0 = (q==0) ? t : (t*2);
                int k1 = k0 | ri;
                cpx a = make_float2(st.vr[k0], st.vi[k0]);
                cpx b = make_float2(st.vr[k1], st.vi[k1]);
                cpx n0 = make_float2(0.f,0.f), n1 = make_float2(0.f,0.f);
                cmac(n0, U00, a); cmac(n0, U01, b);
                cmac(n1, U10, a); cmac(n1, U11, b);
                st.vr[k0]=n0.x; st.vi[k0]=n0.y; st.vr[k1]=n1.x; st.vi[k1]=n1.y;
            }
        }
    }

    // ---- phase 2: IsingXX, tournament order (all commute; disjoint rounds -> ILP);
    //      coefficients hoisted into registers so gates aren't fronted by LDS latency ----
    {
        constexpr int XI[28] = {0,1,2,3, 1,0,3,4, 2,1,0,5, 3,2,1,0, 4,3,2,0, 5,4,0,1, 6,0,1,2};
        constexpr int XJ[28] = {7,6,5,4, 7,2,6,5, 7,3,4,6, 7,4,5,6, 7,5,6,1, 7,6,3,2, 7,5,4,3};
        cpx csx[28];
        #pragma unroll
        for (int g=0; g<28; ++g) csx[g] = tc[XI[g]*8 + XJ[g]];
        #pragma unroll
        for (int g=0; g<28; ++g) gXX(st, XI[g], XJ[g], csx[g].x, csx[g].y);
    }

    // ---- phase 3: composite conv+pool per active pair, reference order ----
    {
        constexpr int PI3[28] = {0,0,0,0,0,0,0, 1,1,1,1,1,1, 2,2,2,2,2, 3,3,3,3, 4,4,4, 5,5, 6};
        constexpr int PJ3[28] = {1,2,3,4,5,6,7, 2,3,4,5,6,7, 3,4,5,6,7, 4,5,6,7, 5,6,7, 6,7, 7};
        #pragma unroll
        for (int p=0;p<28;++p) {
            if ((pm >> p) & 1u) {
                const int i = PI3[p], j = PJ3[p];
                if (i >= 2)      applyBlockLL(st, bmat, p, i, j);
                else if (j >= 2) applyBlockMixed(st, bmat, p, i, j);
                else             applyBlock01(st, bmat, p);
            }
        }
    }

    // ---- write statevector ----
    #pragma unroll
    for (int k=0;k<4;++k) psi[k*64+lane] = make_float2(st.vr[k], st.vi[k]);
}

// rho[r,c] = psi[r] * conj(psi[c]); planar: out[0:65536]=real, out[65536:]=imag
__global__ __launch_bounds__(256) void outer_planar(const float2* __restrict__ psi,
                                                    float* __restrict__ out) {
    int c = threadIdx.x;
    int r = blockIdx.x;
    float2 pr = psi[r];
    float2 pc = psi[c];
    int idx = (r<<8) + c;
    out[idx]         = pr.x*pc.x + pr.y*pc.y;
    out[idx + 65536] = pr.y*pc.x - pr.x*pc.y;
}

__global__ __launch_bounds__(256) void outer_real(const float2* __restrict__ psi,
                                                  float* __restrict__ out) {
    int c = threadIdx.x;
    int r = blockIdx.x;
    float2 pr = psi[r];
    float2 pc = psi[c];
    out[(r<<8) + c] = pr.x*pc.x + pr.y*pc.y;
}

__global__ __launch_bounds__(256) void outer_interleaved(const float2* __restrict__ psi,
                                                         float2* __restrict__ out) {
    int c = threadIdx.x;
    int r = blockIdx.x;
    float2 pr = psi[r];
    float2 pc = psi[c];
    out[(r<<8) + c] = make_float2(pr.x*pc.x + pr.y*pc.y, pr.y*pc.x - pr.x*pc.y);
}

extern "C" void kernel_launch(void* const* d_in, const int* in_sizes, int n_in,
                              void* d_out, int out_size, void* d_ws, size_t ws_size,
                              hipStream_t stream) {
    (void)in_sizes; (void)n_in; (void)ws_size;
    const float* x  = (const float*)d_in[0];
    const float* w  = (const float*)d_in[1];
    const float* cp = (const float*)d_in[2];
    float2* psi = (float2*)d_ws;   // 2 KB scratch
    hipLaunchKernelGGL(evolve_kernel, dim3(1), dim3(64), 0, stream, x, w, cp, psi);
    if (out_size == 65536) {
        hipLaunchKernelGGL(outer_real, dim3(256), dim3(256), 0, stream, psi, (float*)d_out);
    } else if (out_size == 131072) {
        hipLaunchKernelGGL(outer_planar, dim3(256), dim3(256), 0, stream, psi, (float*)d_out);
    } else {
        hipLaunchKernelGGL(outer_interleaved, dim3(256), dim3(256), 0, stream, psi, (float2*)d_out);
    }
}